// Round 19
// baseline (169.935 us; speedup 1.0000x reference)
//
#include <hip/hip_runtime.h>
#include <stdint.h>

#define BATCH 8
#define NPRI 100000
#define NGT 16
#define NCLS 41
#define F_POS_TH 0.5f
#define F_NEG_TH 0.4f

static constexpr int CTPB = 256;
static constexpr int CBLK = (NPRI + CTPB - 1) / CTPB;  // 391 blocks per batch
static constexpr int H0BIN = 256;                      // lvl0 hist bins (key top-8 bits)
static constexpr int NBIN = 4096;                      // k_select lvl1/2 bins

// ---- workspace layout (bytes) ----
static constexpr size_t OFF_KEY  = 0;                               // u32 [B*P] lc bits
static constexpr size_t OFF_GTC  = OFF_KEY + (size_t)BATCH*NPRI*4;  // u64 [B*16]
static constexpr size_t OFF_HG   = OFF_GTC + BATCH*NGT*8;           // u32 [B][256] lvl0 hist
static constexpr size_t OFF_NPOS = OFF_HG + (size_t)BATCH*H0BIN*4;  // u32 [B]
static constexpr size_t OFF_SL1  = OFF_NPOS + BATCH*4;              // f32 [B]
static constexpr size_t OFF_CEP  = OFF_SL1  + BATCH*4;              // f32 [B]
static constexpr size_t OFF_NEG  = OFF_CEP  + BATCH*4;              // f32 [B]
static constexpr size_t OFF_FTK  = OFF_NEG  + BATCH*4;              // u32 [1]
static constexpr int ZERO_U32 = (int)((OFF_FTK + 4 - OFF_HG) / 4);  // hist + scalars

typedef float f32x4 __attribute__((ext_vector_type(4)));

__device__ inline float smoothl1(float d) {
  float a = fabsf(d);
  return a < 1.f ? 0.5f * d * d : a - 0.5f;
}
__device__ inline float sl1_terms(f32x4 pv, f32x4 ld, f32x4 gv) {
  float tx = ((gv[0] + gv[2]) * 0.5f - pv[0]) / (0.1f * pv[2]);
  float ty = ((gv[1] + gv[3]) * 0.5f - pv[1]) / (0.1f * pv[3]);
  float tw = __logf(fmaxf((gv[2] - gv[0]) / pv[2], 1e-8f)) / 0.2f;
  float th = __logf(fmaxf((gv[3] - gv[1]) / pv[3], 1e-8f)) / 0.2f;
  return smoothl1(ld[0] - tx) + smoothl1(ld[1] - ty)
       + smoothl1(ld[2] - tw) + smoothl1(ld[3] - th);
}
__device__ inline float aload_f32(const float* p) {
  return __hip_atomic_load(p, __ATOMIC_RELAXED, __HIP_MEMORY_SCOPE_AGENT);
}
__device__ inline unsigned aload_u32(const unsigned* p) {
  return __hip_atomic_load(p, __ATOMIC_RELAXED, __HIP_MEMORY_SCOPE_AGENT);
}

// ---------------- K_init: zero hist+scalars, gtc baseline ----------------
// gtc re-based every call: ws poison 0xAA.. would win atomicMax otherwise.
__global__ void k_init(unsigned* __restrict__ z, unsigned long long* __restrict__ gtc) {
  int t = threadIdx.x;  // 512 threads
  for (int i = t; i < ZERO_U32; i += 512) z[i] = 0u;
  if (t < BATCH * NGT) gtc[t] = 0xFFFFFFFFull;  // (iou=0)<<32 | (0xFFFFFFFF - p=0)
}

// ---------------- K_conf: per-lane row processing, float4 loads, no staging ----------------
// Each thread owns one prior's 41-float row: 10x float4 + 1 scalar, all
// independent (pure-VALU consumers -> in-order vmcnt keeps later loads in
// flight while earlier ones are consumed). No LDS row machinery, no barriers
// in the hot path. Per-gt argmax fused via LDS best[16]; force-match fixup
// remains in k_select's prologue.
__global__ __launch_bounds__(CTPB) void k_conf(
    const float* __restrict__ loc, const float* __restrict__ conf,
    const float* __restrict__ priors, const float* __restrict__ gtb,
    const int* __restrict__ gtl,
    unsigned* __restrict__ key, unsigned* __restrict__ histg,
    unsigned long long* __restrict__ gtc,
    unsigned* __restrict__ npos, float* __restrict__ sl1sum, float* __restrict__ cepos) {
  __shared__ unsigned hcb[H0BIN];
  __shared__ unsigned long long best[NGT];
  __shared__ float redS[4], redC[4]; __shared__ unsigned redP[4];
  const int t = threadIdx.x, w = t >> 6, l = t & 63;
  const int b = blockIdx.y;
  const int p = blockIdx.x * CTPB + t;
  const bool valid = p < NPRI;
  const int pc = valid ? p : NPRI - 1;
  hcb[t] = 0u;                      // t < 256 == H0BIN
  if (t < NGT) best[t] = 0;
  __syncthreads();
  float accS = 0.f, accC = 0.f; unsigned accP = 0;
  // ---- row loads: 10 x float4 (4B-aligned, stride 164B) + 1 tail scalar ----
  const float* row = conf + ((size_t)b * NPRI + pc) * NCLS;
  f32x4 a0 = *(const f32x4*)(row + 0);
  f32x4 a1 = *(const f32x4*)(row + 4);
  f32x4 a2 = *(const f32x4*)(row + 8);
  f32x4 a3 = *(const f32x4*)(row + 12);
  f32x4 a4 = *(const f32x4*)(row + 16);
  f32x4 a5 = *(const f32x4*)(row + 20);
  f32x4 a6 = *(const f32x4*)(row + 24);
  f32x4 a7 = *(const f32x4*)(row + 28);
  f32x4 a8 = *(const f32x4*)(row + 32);
  f32x4 a9 = *(const f32x4*)(row + 36);
  float a40 = row[40];
  const f32x4 pv = ((const f32x4*)priors)[pc];
  const f32x4 ld = ((const f32x4*)loc)[(size_t)b * NPRI + pc];
  // ---- per-prior match + fused per-gt argmax (overlaps load latency) ----
  float px1 = pv[0] - 0.5f * pv[2], py1 = pv[1] - 0.5f * pv[3];
  float px2 = pv[0] + 0.5f * pv[2], py2 = pv[1] + 0.5f * pv[3];
  float parea = (px2 - px1) * (py2 - py1);
  float bov = 0.f; int g = 0;
#pragma unroll
  for (int gg = 0; gg < NGT; gg++) {
    const f32x4 gv = ((const f32x4*)gtb)[b * NGT + gg];  // uniform: s_loads
    float ix = fmaxf(fminf(px2, gv[2]) - fmaxf(px1, gv[0]), 0.f);
    float iy = fmaxf(fminf(py2, gv[3]) - fmaxf(py1, gv[1]), 0.f);
    float inter = ix * iy;
    float garea = (gv[2] - gv[0]) * (gv[3] - gv[1]);
    float iou = inter / (parea + garea - inter);
    if (iou > bov) { bov = iou; g = gg; }
    if (valid && iou > 0.f) {
      unsigned long long comp = ((unsigned long long)__float_as_uint(iou) << 32)
                              | (unsigned long long)(0xFFFFFFFFu - (unsigned)p);
      if (comp > best[gg]) atomicMax(&best[gg], comp);
    }
  }
  // ---- exp-sum entirely in registers (|x|<~7: direct sum safe in f32) ----
  float s = 0.f;
#pragma unroll
  for (int e = 0; e < 4; e++) s += __expf(a0[e]);
#pragma unroll
  for (int e = 0; e < 4; e++) s += __expf(a1[e]);
#pragma unroll
  for (int e = 0; e < 4; e++) s += __expf(a2[e]);
#pragma unroll
  for (int e = 0; e < 4; e++) s += __expf(a3[e]);
#pragma unroll
  for (int e = 0; e < 4; e++) s += __expf(a4[e]);
#pragma unroll
  for (int e = 0; e < 4; e++) s += __expf(a5[e]);
#pragma unroll
  for (int e = 0; e < 4; e++) s += __expf(a6[e]);
#pragma unroll
  for (int e = 0; e < 4; e++) s += __expf(a7[e]);
#pragma unroll
  for (int e = 0; e < 4; e++) s += __expf(a8[e]);
#pragma unroll
  for (int e = 0; e < 4; e++) s += __expf(a9[e]);
  s += __expf(a40);
  float lse = __logf(s);
  unsigned kkreg = 0u;
  if (valid) {
    int c = gtl[b * NGT + g];
    if (bov < F_POS_TH) c = -1;
    if (bov < F_NEG_TH) c = 0;
    kkreg = (c == 0) ? __float_as_uint(lse - a0[0]) : 0u;
    key[(size_t)b * NPRI + p] = kkreg;
    if (c > 0) {
      accP = 1;
      float rc = conf[((size_t)b * NPRI + p) * NCLS + c];  // rare scattered re-read
      accC = lse - rc;
      const f32x4 gvb = ((const f32x4*)gtb)[b * NGT + g];
      accS = sl1_terms(pv, ld, gvb);
    }
  }
  // lvl0 hist, hot bins (0x40 and 0) ballot-aggregated per wave
  unsigned bin = kkreg >> 24;
  unsigned long long m40 = __ballot(valid && kkreg != 0u && bin == 0x40u);
  unsigned long long m00 = __ballot(valid && kkreg == 0u);
  if (m40 && l == __ffsll((long long)m40) - 1)
    atomicAdd(&hcb[0x40], (unsigned)__popcll(m40));
  if (m00 && l == __ffsll((long long)m00) - 1)
    atomicAdd(&hcb[0], (unsigned)__popcll(m00));
  if (valid && kkreg != 0u && bin != 0x40u) atomicAdd(&hcb[bin], 1u);
  __syncthreads();  // hcb/best atomics visible block-wide
  if (t < NGT && best[t] != 0) atomicMax(&gtc[b * NGT + t], best[t]);
  { unsigned v = hcb[t]; if (v) atomicAdd(&histg[b * H0BIN + t], v); }
  // block reduction, one atomic set per block
  float vs = accS, vc = accC; unsigned vp = accP;
#pragma unroll
  for (int off = 32; off; off >>= 1) {
    vs += __shfl_down(vs, off, 64);
    vc += __shfl_down(vc, off, 64);
    vp += __shfl_down(vp, off, 64);
  }
  if (l == 0) { redS[w] = vs; redC[w] = vc; redP[w] = vp; }
  __syncthreads();
  if (t == 0) {
    float ts = redS[0] + redS[1] + redS[2] + redS[3];
    float tc = redC[0] + redC[1] + redC[2] + redC[3];
    unsigned tp = redP[0] + redP[1] + redP[2] + redP[3];
    if (tp) atomicAdd(&npos[b], tp);
    if (ts != 0.f) atomicAdd(&sl1sum[b], ts);
    if (tc != 0.f) atomicAdd(&cepos[b], tc);
  }
}

// ---------------- K_select: PARALLEL force-fixup + 3-level radix + exact-T sum ----------------
__global__ __launch_bounds__(1024) void k_select(
    const float* __restrict__ loc, const float* __restrict__ conf,
    const float* __restrict__ priors, const float* __restrict__ gtb,
    const int* __restrict__ gtl, const unsigned long long* __restrict__ gtc,
    unsigned* __restrict__ key, const unsigned* __restrict__ histg,
    unsigned* __restrict__ npos, float* __restrict__ sl1sum,
    float* __restrict__ cepos, float* __restrict__ negsum,
    unsigned* __restrict__ final_tk, float* __restrict__ out) {
  __shared__ unsigned hc[NBIN];
  __shared__ unsigned h0s[H0BIN];
  __shared__ unsigned pcs[256], sc[256];
  __shared__ int wA; __shared__ unsigned kexA;
  __shared__ unsigned kS, prefS;
  __shared__ float redf[16];
  __shared__ unsigned pw16[NGT];
  int b = blockIdx.x, t = threadIdx.x;
  if (t < H0BIN) h0s[t] = histg[b * H0BIN + t];
  if (t < NGT)
    pw16[t] = 0xFFFFFFFFu - (unsigned)(gtc[b * NGT + t] & 0xFFFFFFFFull);
  if (t == 0) { kS = 0u; prefS = 0u; wA = -1; }
  __syncthreads();
  // ---- parallel fixup (lanes 0..15 of wave 0 carry work; others contribute 0) ----
  float d_sl = 0.f, d_ce = 0.f; int d_np = 0;
  if (t < NGT) {
    unsigned p = pw16[t];
    bool is_first = true, is_last = true;
    for (int j = 0; j < NGT; j++) {
      if (j < t && pw16[j] == p) is_first = false;
      if (j > t && pw16[j] == p) is_last = false;
    }
    const float* row = conf + ((size_t)b * NPRI + p) * NCLS;
    float s = 0.f;
    for (int j = 0; j < NCLS; j++) s += __expf(row[j]);
    float lse = __logf(s);
    f32x4 pv = ((const f32x4*)priors)[p];
    f32x4 ldv = ((const f32x4*)loc)[(size_t)b * NPRI + p];
    if (is_first) {
      // recompute original match of prior p (same math as k_conf)
      float px1 = pv[0] - 0.5f * pv[2], py1 = pv[1] - 0.5f * pv[3];
      float px2 = pv[0] + 0.5f * pv[2], py2 = pv[1] + 0.5f * pv[3];
      float parea = (px2 - px1) * (py2 - py1);
      float bov = 0.f; int gold = 0;
      for (int gg = 0; gg < NGT; gg++) {
        const f32x4 gv = ((const f32x4*)gtb)[b * NGT + gg];
        float ix = fmaxf(fminf(px2, gv[2]) - fmaxf(px1, gv[0]), 0.f);
        float iy = fmaxf(fminf(py2, gv[3]) - fmaxf(py1, gv[1]), 0.f);
        float inter = ix * iy;
        float garea = (gv[2] - gv[0]) * (gv[3] - gv[1]);
        float iou = inter / (parea + garea - inter);
        if (iou > bov) { bov = iou; gold = gg; }
      }
      int cold = (bov < F_NEG_TH) ? 0 : ((bov < F_POS_TH) ? -1 : gtl[b * NGT + gold]);
      if (cold == 0) {          // was background: move its hist count to bin 0
        unsigned ko = key[(size_t)b * NPRI + p];
        atomicSub(&h0s[ko >> 24], 1u);
        atomicAdd(&h0s[0], 1u);
      } else if (cold > 0) {    // was positive with gold: undo
        d_np -= 1;
        d_ce -= lse - row[cold];
        d_sl -= sl1_terms(pv, ldv, ((const f32x4*)gtb)[b * NGT + gold]);
      }
      d_np += 1;
      key[(size_t)b * NPRI + p] = 0u;  // idempotent across duplicates
    }
    if (is_last) {              // final assignment: gt = t (last-wins)
      d_ce += lse - row[gtl[b * NGT + t]];
      d_sl += sl1_terms(pv, ldv, ((const f32x4*)gtb)[b * NGT + t]);
    }
  }
  if (t < 64) {                 // wave 0 reduce (lanes >=16 carry zeros)
    float vs = d_sl, vc = d_ce; int vp = d_np;
#pragma unroll
    for (int off = 32; off; off >>= 1) {
      vs += __shfl_down(vs, off, 64);
      vc += __shfl_down(vc, off, 64);
      vp += __shfl_down(vp, off, 64);
    }
    if (t == 0) {
      npos[b] = (unsigned)((int)npos[b] + vp);
      sl1sum[b] += vs;
      cepos[b] += vc;
    }
  }
  __syncthreads();
  unsigned k0 = min(3u * npos[b], (unsigned)(NPRI - 1));
  const int iters = (NPRI + 1023) / 1024;
  // ---- lvl0: 256-bin hist (fixed), suffix scan ----
  if (t < 256) { unsigned v = h0s[t]; pcs[t] = v; sc[t] = v; }
  __syncthreads();
  for (int off = 1; off < 256; off <<= 1) {
    unsigned v = 0;
    if (t < 256) v = (t + off < 256) ? sc[t + off] : 0u;
    __syncthreads();
    if (t < 256) sc[t] += v;
    __syncthreads();
  }
  if (t < 256) {
    unsigned excl = sc[t] - pcs[t];
    if (k0 > 0 && excl < k0 && k0 <= excl + pcs[t]) { wA = t; kexA = excl; }
  }
  __syncthreads();
  if (t == 0 && wA >= 0) { prefS = ((unsigned)wA) << 24; kS = k0 - kexA; }
  __syncthreads();
  // ---- lvl1 [23:12] / lvl2 [11:0]: scans over near-uniform mantissa bits ----
  for (int lvl = 1; lvl <= 2; lvl++) {
    unsigned k = kS;
    int shift = (lvl == 1) ? 12 : 0;
    int lowcut = (lvl == 1) ? 24 : 12;
    for (int i = t; i < NBIN; i += 1024) hc[i] = 0u;
    if (t == 0) wA = -1;
    __syncthreads();
    unsigned pre = prefS >> lowcut;
    if (k > 0) {
      for (int n = 0; n < iters; n++) {
        int i = n * 1024 + t;
        if (i < NPRI) {
          unsigned kk = key[(size_t)b * NPRI + i];
          if ((kk >> lowcut) == pre) atomicAdd(&hc[(kk >> shift) & 0xFFFu], 1u);
        }
      }
    }
    __syncthreads();
    if (t < 256) {
      unsigned cs = 0;
#pragma unroll
      for (int u = 0; u < 16; u++) cs += hc[t * 16 + u];
      pcs[t] = cs; sc[t] = cs;
    }
    __syncthreads();
    for (int off = 1; off < 256; off <<= 1) {
      unsigned v = 0;
      if (t < 256) v = (t + off < 256) ? sc[t + off] : 0u;
      __syncthreads();
      if (t < 256) sc[t] += v;
      __syncthreads();
    }
    if (t < 256) {
      unsigned excl = sc[t] - pcs[t];
      if (k > 0 && excl < k && k <= excl + pcs[t]) { wA = t; kexA = excl; }
    }
    __syncthreads();
    if (wA >= 0 && t < 64) {
      int w = wA; unsigned exw = kexA;
      unsigned v = (t < 16) ? hc[w * 16 + t] : 0u;
      unsigned sufv = v;
#pragma unroll
      for (int off = 1; off < 16; off <<= 1) {
        unsigned x = __shfl_down(sufv, off, 64);
        if (t + off < 16) sufv += x;
      }
      unsigned excl2 = exw + (sufv - v);
      if (t < 16 && excl2 < k && k <= excl2 + v) {
        prefS |= ((unsigned)(w * 16 + t)) << shift;
        kS = k - excl2;
      }
    }
    __syncthreads();
  }
  unsigned Tu = prefS;   // exact threshold key value
  unsigned tie = kS;
  float acc = 0.f;
  if (k0 > 0) {
    for (int n = 0; n < iters; n++) {
      int i = n * 1024 + t;
      if (i < NPRI) {
        unsigned kk = key[(size_t)b * NPRI + i];
        if (kk > Tu) acc += __uint_as_float(kk);  // uint order == float order
      }
    }
  }
#pragma unroll
  for (int off = 32; off; off >>= 1) acc += __shfl_down(acc, off, 64);
  if ((t & 63) == 0) redf[t >> 6] = acc;
  __syncthreads();
  if (t == 0) {
    float tot = 0.f;
    for (int wv = 0; wv < 16; wv++) tot += redf[wv];
    if (k0 > 0) tot += (float)tie * __uint_as_float(Tu);
    negsum[b] = tot;
    __threadfence();                       // covers fixup + negsum writes
    unsigned r2 = atomicAdd(final_tk, 1u);
    if (r2 == BATCH - 1) {                 // globally-last block combines
      __threadfence();
      float lb = 0.f, ctot = 0.f; unsigned tp = 0;
      for (int bb = 0; bb < BATCH; bb++) {
        unsigned nb = aload_u32(&npos[bb]);
        lb += aload_f32(&sl1sum[bb]) / fmaxf((float)nb, 1.f);
        tp += nb;
        ctot += aload_f32(&cepos[bb]) + aload_f32(&negsum[bb]);
      }
      out[0] = (1.5f * lb + ctot / fmaxf((float)tp, 1.f)) / (float)BATCH;
      *final_tk = 0;                       // self-clean for next replay
    }
  }
}

extern "C" void kernel_launch(void* const* d_in, const int* in_sizes, int n_in,
                              void* d_out, int out_size, void* d_ws, size_t ws_size,
                              hipStream_t stream) {
  const float* loc = (const float*)d_in[0];
  const float* conf = (const float*)d_in[1];
  const float* priors = (const float*)d_in[2];
  const float* gtb = (const float*)d_in[3];
  const int* gtl = (const int*)d_in[4];
  char* ws = (char*)d_ws;
  unsigned* key = (unsigned*)(ws + OFF_KEY);
  unsigned long long* gtc = (unsigned long long*)(ws + OFF_GTC);
  unsigned* histg = (unsigned*)(ws + OFF_HG);
  unsigned* npos = (unsigned*)(ws + OFF_NPOS);
  float* sl1sum = (float*)(ws + OFF_SL1);
  float* cepos = (float*)(ws + OFF_CEP);
  float* negsum = (float*)(ws + OFF_NEG);
  unsigned* final_tk = (unsigned*)(ws + OFF_FTK);
  float* out = (float*)d_out;

  k_init<<<1, 512, 0, stream>>>(histg, gtc);
  dim3 gridC(CBLK, BATCH);
  k_conf<<<gridC, CTPB, 0, stream>>>(loc, conf, priors, gtb, gtl,
                                     key, histg, gtc, npos, sl1sum, cepos);
  k_select<<<BATCH, 1024, 0, stream>>>(loc, conf, priors, gtb, gtl, gtc,
                                       key, histg, npos, sl1sum, cepos,
                                       negsum, final_tk, out);
}

// Round 20
// 169.447 us; speedup vs baseline: 1.0029x; 1.0029x over previous
//
#include <hip/hip_runtime.h>
#include <stdint.h>

#define BATCH 8
#define NPRI 100000
#define NGT 16
#define NCLS 41
#define F_POS_TH 0.5f
#define F_NEG_TH 0.4f

static constexpr int CTPB = 256;
static constexpr int CBLK = (NPRI + CTPB - 1) / CTPB;  // 391 blocks per batch
static constexpr int H0BIN = 256;                      // lvl0 hist bins (key top-8 bits)
static constexpr int NBIN = 4096;                      // k_select lvl1/2 bins

// ---- workspace layout (bytes) ----
static constexpr size_t OFF_KEY  = 0;                               // u32 [B*P] lc bits
static constexpr size_t OFF_GTC  = OFF_KEY + (size_t)BATCH*NPRI*4;  // u64 [B*16]
static constexpr size_t OFF_HG   = OFF_GTC + BATCH*NGT*8;           // u32 [B][256] lvl0 hist
static constexpr size_t OFF_NPOS = OFF_HG + (size_t)BATCH*H0BIN*4;  // u32 [B]
static constexpr size_t OFF_SL1  = OFF_NPOS + BATCH*4;              // f32 [B]
static constexpr size_t OFF_CEP  = OFF_SL1  + BATCH*4;              // f32 [B]
static constexpr size_t OFF_NEG  = OFF_CEP  + BATCH*4;              // f32 [B]
static constexpr size_t OFF_FTK  = OFF_NEG  + BATCH*4;              // u32 [1]
static constexpr int ZERO_U32 = (int)((OFF_FTK + 4 - OFF_HG) / 4);  // hist + scalars

typedef float f32x4 __attribute__((ext_vector_type(4)));

__device__ inline float smoothl1(float d) {
  float a = fabsf(d);
  return a < 1.f ? 0.5f * d * d : a - 0.5f;
}
__device__ inline float sl1_terms(f32x4 pv, f32x4 ld, f32x4 gv) {
  float tx = ((gv[0] + gv[2]) * 0.5f - pv[0]) / (0.1f * pv[2]);
  float ty = ((gv[1] + gv[3]) * 0.5f - pv[1]) / (0.1f * pv[3]);
  float tw = __logf(fmaxf((gv[2] - gv[0]) / pv[2], 1e-8f)) / 0.2f;
  float th = __logf(fmaxf((gv[3] - gv[1]) / pv[3], 1e-8f)) / 0.2f;
  return smoothl1(ld[0] - tx) + smoothl1(ld[1] - ty)
       + smoothl1(ld[2] - tw) + smoothl1(ld[3] - th);
}
__device__ inline float aload_f32(const float* p) {
  return __hip_atomic_load(p, __ATOMIC_RELAXED, __HIP_MEMORY_SCOPE_AGENT);
}
__device__ inline unsigned aload_u32(const unsigned* p) {
  return __hip_atomic_load(p, __ATOMIC_RELAXED, __HIP_MEMORY_SCOPE_AGENT);
}

// ---------------- K_init: zero hist+scalars, gtc baseline ----------------
// gtc re-based every call: ws poison 0xAA.. would win atomicMax otherwise.
__global__ void k_init(unsigned* __restrict__ z, unsigned long long* __restrict__ gtc) {
  int t = threadIdx.x;  // 512 threads
  for (int i = t; i < ZERO_U32; i += 512) z[i] = 0u;
  if (t < BATCH * NGT) gtc[t] = 0xFFFFFFFFull;  // (iou=0)<<32 | (0xFFFFFFFF - p=0)
}

// ---------------- K_conf: per-lane rows, ALL loads pinned live via asm ----------------
// Round-19 structure + the one untested lever: a keep-alive asm consuming every
// loaded register AFTER the match loop forces (a) all 11 row loads + pv/ld to
// issue before any wait, (b) a single s_waitcnt for the batch (loads cannot be
// sunk past an asm that reads them). launch_bounds(,2) grants the ~60+ VGPRs.
__global__ __launch_bounds__(CTPB, 2) void k_conf(
    const float* __restrict__ loc, const float* __restrict__ conf,
    const float* __restrict__ priors, const float* __restrict__ gtb,
    const int* __restrict__ gtl,
    unsigned* __restrict__ key, unsigned* __restrict__ histg,
    unsigned long long* __restrict__ gtc,
    unsigned* __restrict__ npos, float* __restrict__ sl1sum, float* __restrict__ cepos) {
  __shared__ unsigned hcb[H0BIN];
  __shared__ unsigned long long best[NGT];
  __shared__ float redS[4], redC[4]; __shared__ unsigned redP[4];
  const int t = threadIdx.x, w = t >> 6, l = t & 63;
  const int b = blockIdx.y;
  const int p = blockIdx.x * CTPB + t;
  const bool valid = p < NPRI;
  const int pc = valid ? p : NPRI - 1;
  hcb[t] = 0u;                      // t < 256 == H0BIN
  if (t < NGT) best[t] = 0;
  __syncthreads();
  float accS = 0.f, accC = 0.f; unsigned accP = 0;
  // ---- issue ALL row loads first (10 x float4 + tail scalar) ----
  const float* row = conf + ((size_t)b * NPRI + pc) * NCLS;
  f32x4 a0 = *(const f32x4*)(row + 0);
  f32x4 a1 = *(const f32x4*)(row + 4);
  f32x4 a2 = *(const f32x4*)(row + 8);
  f32x4 a3 = *(const f32x4*)(row + 12);
  f32x4 a4 = *(const f32x4*)(row + 16);
  f32x4 a5 = *(const f32x4*)(row + 20);
  f32x4 a6 = *(const f32x4*)(row + 24);
  f32x4 a7 = *(const f32x4*)(row + 28);
  f32x4 a8 = *(const f32x4*)(row + 32);
  f32x4 a9 = *(const f32x4*)(row + 36);
  float a40 = row[40];
  const f32x4 pv = ((const f32x4*)priors)[pc];
  const f32x4 ld = ((const f32x4*)loc)[(size_t)b * NPRI + pc];
  // ---- match loop overlaps the in-flight loads (pure VALU + uniform s_loads) ----
  float px1 = pv[0] - 0.5f * pv[2], py1 = pv[1] - 0.5f * pv[3];
  float px2 = pv[0] + 0.5f * pv[2], py2 = pv[1] + 0.5f * pv[3];
  float parea = (px2 - px1) * (py2 - py1);
  float bov = 0.f; int g = 0;
#pragma unroll
  for (int gg = 0; gg < NGT; gg++) {
    const f32x4 gv = ((const f32x4*)gtb)[b * NGT + gg];
    float ix = fmaxf(fminf(px2, gv[2]) - fmaxf(px1, gv[0]), 0.f);
    float iy = fmaxf(fminf(py2, gv[3]) - fmaxf(py1, gv[1]), 0.f);
    float inter = ix * iy;
    float garea = (gv[2] - gv[0]) * (gv[3] - gv[1]);
    float iou = inter / (parea + garea - inter);
    if (iou > bov) { bov = iou; g = gg; }
    if (valid && iou > 0.f) {
      unsigned long long comp = ((unsigned long long)__float_as_uint(iou) << 32)
                              | (unsigned long long)(0xFFFFFFFFu - (unsigned)p);
      if (comp > best[gg]) atomicMax(&best[gg], comp);
    }
  }
  // ---- keep-alive: forces all loads live + one waitcnt here ----
  asm volatile("" :: "v"(a0), "v"(a1), "v"(a2), "v"(a3), "v"(a4),
                     "v"(a5), "v"(a6), "v"(a7), "v"(a8), "v"(a9),
                     "v"(a40));
  // ---- exp-sum entirely in registers (|x|<~7: direct sum safe in f32) ----
  float s = 0.f;
#pragma unroll
  for (int e = 0; e < 4; e++) s += __expf(a0[e]);
#pragma unroll
  for (int e = 0; e < 4; e++) s += __expf(a1[e]);
#pragma unroll
  for (int e = 0; e < 4; e++) s += __expf(a2[e]);
#pragma unroll
  for (int e = 0; e < 4; e++) s += __expf(a3[e]);
#pragma unroll
  for (int e = 0; e < 4; e++) s += __expf(a4[e]);
#pragma unroll
  for (int e = 0; e < 4; e++) s += __expf(a5[e]);
#pragma unroll
  for (int e = 0; e < 4; e++) s += __expf(a6[e]);
#pragma unroll
  for (int e = 0; e < 4; e++) s += __expf(a7[e]);
#pragma unroll
  for (int e = 0; e < 4; e++) s += __expf(a8[e]);
#pragma unroll
  for (int e = 0; e < 4; e++) s += __expf(a9[e]);
  s += __expf(a40);
  float lse = __logf(s);
  unsigned kkreg = 0u;
  if (valid) {
    int c = gtl[b * NGT + g];
    if (bov < F_POS_TH) c = -1;
    if (bov < F_NEG_TH) c = 0;
    kkreg = (c == 0) ? __float_as_uint(lse - a0[0]) : 0u;
    key[(size_t)b * NPRI + p] = kkreg;
    if (c > 0) {
      accP = 1;
      float rc = conf[((size_t)b * NPRI + p) * NCLS + c];  // rare scattered re-read
      accC = lse - rc;
      const f32x4 gvb = ((const f32x4*)gtb)[b * NGT + g];
      accS = sl1_terms(pv, ld, gvb);
    }
  }
  // lvl0 hist, hot bins (0x40 and 0) ballot-aggregated per wave
  unsigned bin = kkreg >> 24;
  unsigned long long m40 = __ballot(valid && kkreg != 0u && bin == 0x40u);
  unsigned long long m00 = __ballot(valid && kkreg == 0u);
  if (m40 && l == __ffsll((long long)m40) - 1)
    atomicAdd(&hcb[0x40], (unsigned)__popcll(m40));
  if (m00 && l == __ffsll((long long)m00) - 1)
    atomicAdd(&hcb[0], (unsigned)__popcll(m00));
  if (valid && kkreg != 0u && bin != 0x40u) atomicAdd(&hcb[bin], 1u);
  __syncthreads();  // hcb/best atomics visible block-wide
  if (t < NGT && best[t] != 0) atomicMax(&gtc[b * NGT + t], best[t]);
  { unsigned v = hcb[t]; if (v) atomicAdd(&histg[b * H0BIN + t], v); }
  // block reduction, one atomic set per block
  float vs = accS, vc = accC; unsigned vp = accP;
#pragma unroll
  for (int off = 32; off; off >>= 1) {
    vs += __shfl_down(vs, off, 64);
    vc += __shfl_down(vc, off, 64);
    vp += __shfl_down(vp, off, 64);
  }
  if (l == 0) { redS[w] = vs; redC[w] = vc; redP[w] = vp; }
  __syncthreads();
  if (t == 0) {
    float ts = redS[0] + redS[1] + redS[2] + redS[3];
    float tc = redC[0] + redC[1] + redC[2] + redC[3];
    unsigned tp = redP[0] + redP[1] + redP[2] + redP[3];
    if (tp) atomicAdd(&npos[b], tp);
    if (ts != 0.f) atomicAdd(&sl1sum[b], ts);
    if (tc != 0.f) atomicAdd(&cepos[b], tc);
  }
}

// ---------------- K_select: PARALLEL force-fixup + 3-level radix + exact-T sum ----------------
__global__ __launch_bounds__(1024) void k_select(
    const float* __restrict__ loc, const float* __restrict__ conf,
    const float* __restrict__ priors, const float* __restrict__ gtb,
    const int* __restrict__ gtl, const unsigned long long* __restrict__ gtc,
    unsigned* __restrict__ key, const unsigned* __restrict__ histg,
    unsigned* __restrict__ npos, float* __restrict__ sl1sum,
    float* __restrict__ cepos, float* __restrict__ negsum,
    unsigned* __restrict__ final_tk, float* __restrict__ out) {
  __shared__ unsigned hc[NBIN];
  __shared__ unsigned h0s[H0BIN];
  __shared__ unsigned pcs[256], sc[256];
  __shared__ int wA; __shared__ unsigned kexA;
  __shared__ unsigned kS, prefS;
  __shared__ float redf[16];
  __shared__ unsigned pw16[NGT];
  int b = blockIdx.x, t = threadIdx.x;
  if (t < H0BIN) h0s[t] = histg[b * H0BIN + t];
  if (t < NGT)
    pw16[t] = 0xFFFFFFFFu - (unsigned)(gtc[b * NGT + t] & 0xFFFFFFFFull);
  if (t == 0) { kS = 0u; prefS = 0u; wA = -1; }
  __syncthreads();
  // ---- parallel fixup (lanes 0..15 of wave 0 carry work; others contribute 0) ----
  float d_sl = 0.f, d_ce = 0.f; int d_np = 0;
  if (t < NGT) {
    unsigned p = pw16[t];
    bool is_first = true, is_last = true;
    for (int j = 0; j < NGT; j++) {
      if (j < t && pw16[j] == p) is_first = false;
      if (j > t && pw16[j] == p) is_last = false;
    }
    const float* row = conf + ((size_t)b * NPRI + p) * NCLS;
    float s = 0.f;
    for (int j = 0; j < NCLS; j++) s += __expf(row[j]);
    float lse = __logf(s);
    f32x4 pv = ((const f32x4*)priors)[p];
    f32x4 ldv = ((const f32x4*)loc)[(size_t)b * NPRI + p];
    if (is_first) {
      // recompute original match of prior p (same math as k_conf)
      float px1 = pv[0] - 0.5f * pv[2], py1 = pv[1] - 0.5f * pv[3];
      float px2 = pv[0] + 0.5f * pv[2], py2 = pv[1] + 0.5f * pv[3];
      float parea = (px2 - px1) * (py2 - py1);
      float bov = 0.f; int gold = 0;
      for (int gg = 0; gg < NGT; gg++) {
        const f32x4 gv = ((const f32x4*)gtb)[b * NGT + gg];
        float ix = fmaxf(fminf(px2, gv[2]) - fmaxf(px1, gv[0]), 0.f);
        float iy = fmaxf(fminf(py2, gv[3]) - fmaxf(py1, gv[1]), 0.f);
        float inter = ix * iy;
        float garea = (gv[2] - gv[0]) * (gv[3] - gv[1]);
        float iou = inter / (parea + garea - inter);
        if (iou > bov) { bov = iou; gold = gg; }
      }
      int cold = (bov < F_NEG_TH) ? 0 : ((bov < F_POS_TH) ? -1 : gtl[b * NGT + gold]);
      if (cold == 0) {          // was background: move its hist count to bin 0
        unsigned ko = key[(size_t)b * NPRI + p];
        atomicSub(&h0s[ko >> 24], 1u);
        atomicAdd(&h0s[0], 1u);
      } else if (cold > 0) {    // was positive with gold: undo
        d_np -= 1;
        d_ce -= lse - row[cold];
        d_sl -= sl1_terms(pv, ldv, ((const f32x4*)gtb)[b * NGT + gold]);
      }
      d_np += 1;
      key[(size_t)b * NPRI + p] = 0u;  // idempotent across duplicates
    }
    if (is_last) {              // final assignment: gt = t (last-wins)
      d_ce += lse - row[gtl[b * NGT + t]];
      d_sl += sl1_terms(pv, ldv, ((const f32x4*)gtb)[b * NGT + t]);
    }
  }
  if (t < 64) {                 // wave 0 reduce (lanes >=16 carry zeros)
    float vs = d_sl, vc = d_ce; int vp = d_np;
#pragma unroll
    for (int off = 32; off; off >>= 1) {
      vs += __shfl_down(vs, off, 64);
      vc += __shfl_down(vc, off, 64);
      vp += __shfl_down(vp, off, 64);
    }
    if (t == 0) {
      npos[b] = (unsigned)((int)npos[b] + vp);
      sl1sum[b] += vs;
      cepos[b] += vc;
    }
  }
  __syncthreads();
  unsigned k0 = min(3u * npos[b], (unsigned)(NPRI - 1));
  const int iters = (NPRI + 1023) / 1024;
  // ---- lvl0: 256-bin hist (fixed), suffix scan ----
  if (t < 256) { unsigned v = h0s[t]; pcs[t] = v; sc[t] = v; }
  __syncthreads();
  for (int off = 1; off < 256; off <<= 1) {
    unsigned v = 0;
    if (t < 256) v = (t + off < 256) ? sc[t + off] : 0u;
    __syncthreads();
    if (t < 256) sc[t] += v;
    __syncthreads();
  }
  if (t < 256) {
    unsigned excl = sc[t] - pcs[t];
    if (k0 > 0 && excl < k0 && k0 <= excl + pcs[t]) { wA = t; kexA = excl; }
  }
  __syncthreads();
  if (t == 0 && wA >= 0) { prefS = ((unsigned)wA) << 24; kS = k0 - kexA; }
  __syncthreads();
  // ---- lvl1 [23:12] / lvl2 [11:0]: scans over near-uniform mantissa bits ----
  for (int lvl = 1; lvl <= 2; lvl++) {
    unsigned k = kS;
    int shift = (lvl == 1) ? 12 : 0;
    int lowcut = (lvl == 1) ? 24 : 12;
    for (int i = t; i < NBIN; i += 1024) hc[i] = 0u;
    if (t == 0) wA = -1;
    __syncthreads();
    unsigned pre = prefS >> lowcut;
    if (k > 0) {
      for (int n = 0; n < iters; n++) {
        int i = n * 1024 + t;
        if (i < NPRI) {
          unsigned kk = key[(size_t)b * NPRI + i];
          if ((kk >> lowcut) == pre) atomicAdd(&hc[(kk >> shift) & 0xFFFu], 1u);
        }
      }
    }
    __syncthreads();
    if (t < 256) {
      unsigned cs = 0;
#pragma unroll
      for (int u = 0; u < 16; u++) cs += hc[t * 16 + u];
      pcs[t] = cs; sc[t] = cs;
    }
    __syncthreads();
    for (int off = 1; off < 256; off <<= 1) {
      unsigned v = 0;
      if (t < 256) v = (t + off < 256) ? sc[t + off] : 0u;
      __syncthreads();
      if (t < 256) sc[t] += v;
      __syncthreads();
    }
    if (t < 256) {
      unsigned excl = sc[t] - pcs[t];
      if (k > 0 && excl < k && k <= excl + pcs[t]) { wA = t; kexA = excl; }
    }
    __syncthreads();
    if (wA >= 0 && t < 64) {
      int w = wA; unsigned exw = kexA;
      unsigned v = (t < 16) ? hc[w * 16 + t] : 0u;
      unsigned sufv = v;
#pragma unroll
      for (int off = 1; off < 16; off <<= 1) {
        unsigned x = __shfl_down(sufv, off, 64);
        if (t + off < 16) sufv += x;
      }
      unsigned excl2 = exw + (sufv - v);
      if (t < 16 && excl2 < k && k <= excl2 + v) {
        prefS |= ((unsigned)(w * 16 + t)) << shift;
        kS = k - excl2;
      }
    }
    __syncthreads();
  }
  unsigned Tu = prefS;   // exact threshold key value
  unsigned tie = kS;
  float acc = 0.f;
  if (k0 > 0) {
    for (int n = 0; n < iters; n++) {
      int i = n * 1024 + t;
      if (i < NPRI) {
        unsigned kk = key[(size_t)b * NPRI + i];
        if (kk > Tu) acc += __uint_as_float(kk);  // uint order == float order
      }
    }
  }
#pragma unroll
  for (int off = 32; off; off >>= 1) acc += __shfl_down(acc, off, 64);
  if ((t & 63) == 0) redf[t >> 6] = acc;
  __syncthreads();
  if (t == 0) {
    float tot = 0.f;
    for (int wv = 0; wv < 16; wv++) tot += redf[wv];
    if (k0 > 0) tot += (float)tie * __uint_as_float(Tu);
    negsum[b] = tot;
    __threadfence();                       // covers fixup + negsum writes
    unsigned r2 = atomicAdd(final_tk, 1u);
    if (r2 == BATCH - 1) {                 // globally-last block combines
      __threadfence();
      float lb = 0.f, ctot = 0.f; unsigned tp = 0;
      for (int bb = 0; bb < BATCH; bb++) {
        unsigned nb = aload_u32(&npos[bb]);
        lb += aload_f32(&sl1sum[bb]) / fmaxf((float)nb, 1.f);
        tp += nb;
        ctot += aload_f32(&cepos[bb]) + aload_f32(&negsum[bb]);
      }
      out[0] = (1.5f * lb + ctot / fmaxf((float)tp, 1.f)) / (float)BATCH;
      *final_tk = 0;                       // self-clean for next replay
    }
  }
}

extern "C" void kernel_launch(void* const* d_in, const int* in_sizes, int n_in,
                              void* d_out, int out_size, void* d_ws, size_t ws_size,
                              hipStream_t stream) {
  const float* loc = (const float*)d_in[0];
  const float* conf = (const float*)d_in[1];
  const float* priors = (const float*)d_in[2];
  const float* gtb = (const float*)d_in[3];
  const int* gtl = (const int*)d_in[4];
  char* ws = (char*)d_ws;
  unsigned* key = (unsigned*)(ws + OFF_KEY);
  unsigned long long* gtc = (unsigned long long*)(ws + OFF_GTC);
  unsigned* histg = (unsigned*)(ws + OFF_HG);
  unsigned* npos = (unsigned*)(ws + OFF_NPOS);
  float* sl1sum = (float*)(ws + OFF_SL1);
  float* cepos = (float*)(ws + OFF_CEP);
  float* negsum = (float*)(ws + OFF_NEG);
  unsigned* final_tk = (unsigned*)(ws + OFF_FTK);
  float* out = (float*)d_out;

  k_init<<<1, 512, 0, stream>>>(histg, gtc);
  dim3 gridC(CBLK, BATCH);
  k_conf<<<gridC, CTPB, 0, stream>>>(loc, conf, priors, gtb, gtl,
                                     key, histg, gtc, npos, sl1sum, cepos);
  k_select<<<BATCH, 1024, 0, stream>>>(loc, conf, priors, gtb, gtl, gtc,
                                       key, histg, npos, sl1sum, cepos,
                                       negsum, final_tk, out);
}